// Round 2
// baseline (1288.733 us; speedup 1.0000x reference)
//
#include <hip/hip_runtime.h>

constexpr int LQ = 5440, LIN = 5440;
constexpr int ROWS = 8 * LQ;            // 43520 = batch*len
constexpr int TM = 128, TN = 128, BK = 32;

struct GemmSmem {
  float At[BK][TM + 4];   // A^T tile: [k][row]
  float Wl[BK][TN + 4];   // W tile:   [k][col]
};

// C[128x128] tile of A(row-major, lda=256, K=256) @ W(row-major, ldw=N)
__device__ __forceinline__ void gemm_mainloop(
    const float* __restrict__ A, const float* __restrict__ W,
    int row_base, int n0, int ldw, GemmSmem& s, float (&acc)[8][8]) {
  const int t = threadIdx.x;
  const int tx = t & 15, ty = t >> 4;
  const int row0 = 8 * ty, col0 = 8 * tx;
#pragma unroll
  for (int r = 0; r < 8; ++r)
#pragma unroll
    for (int c = 0; c < 8; ++c) acc[r][c] = 0.f;

  for (int k0 = 0; k0 < 256; k0 += BK) {
    // stage A tile (128 rows x 32 k), transposed into LDS
#pragma unroll
    for (int i = 0; i < 4; ++i) {
      int item = t + 256 * i;                 // 1024 float4 items
      int r = item >> 3, seg = item & 7;
      float4 v = *(const float4*)(A + (size_t)(row_base + r) * 256 + k0 + seg * 4);
      s.At[seg * 4 + 0][r] = v.x;
      s.At[seg * 4 + 1][r] = v.y;
      s.At[seg * 4 + 2][r] = v.z;
      s.At[seg * 4 + 3][r] = v.w;
    }
    // stage W tile (32 k x 128 n)
#pragma unroll
    for (int i = 0; i < 4; ++i) {
      int item = t + 256 * i;
      int kk = item >> 5, seg = item & 31;
      float4 v = *(const float4*)(W + (size_t)(k0 + kk) * ldw + n0 + seg * 4);
      s.Wl[kk][seg * 4 + 0] = v.x;
      s.Wl[kk][seg * 4 + 1] = v.y;
      s.Wl[kk][seg * 4 + 2] = v.z;
      s.Wl[kk][seg * 4 + 3] = v.w;
    }
    __syncthreads();
#pragma unroll
    for (int k = 0; k < BK; ++k) {
      float a[8], w[8];
      *(float4*)&a[0] = *(const float4*)&s.At[k][row0];
      *(float4*)&a[4] = *(const float4*)&s.At[k][row0 + 4];
      *(float4*)&w[0] = *(const float4*)&s.Wl[k][col0];
      *(float4*)&w[4] = *(const float4*)&s.Wl[k][col0 + 4];
#pragma unroll
      for (int r = 0; r < 8; ++r)
#pragma unroll
        for (int c = 0; c < 8; ++c) acc[r][c] += a[r] * w[c];
    }
    __syncthreads();
  }
}

// K1 / K4: plain GEMM + bias (row stride = N = 256)
__global__ __launch_bounds__(256) void gemm_bias_kernel(
    const float* __restrict__ A, const float* __restrict__ W,
    const float* __restrict__ bias, float* __restrict__ Cout, int N) {
  __shared__ GemmSmem s;
  float acc[8][8];
  int row_base = blockIdx.x * TM;
  int n0 = blockIdx.y * TN;
  gemm_mainloop(A, W, row_base, n0, N, s, acc);
  const int t = threadIdx.x;
  const int tx = t & 15, ty = t >> 4;
  const int row0 = 8 * ty, col0 = 8 * tx;
#pragma unroll
  for (int r = 0; r < 8; ++r) {
    int row = row_base + row0 + r;
    float4 o0, o1;
    o0.x = acc[r][0] + bias[n0 + col0 + 0];
    o0.y = acc[r][1] + bias[n0 + col0 + 1];
    o0.z = acc[r][2] + bias[n0 + col0 + 2];
    o0.w = acc[r][3] + bias[n0 + col0 + 3];
    o1.x = acc[r][4] + bias[n0 + col0 + 4];
    o1.y = acc[r][5] + bias[n0 + col0 + 5];
    o1.z = acc[r][6] + bias[n0 + col0 + 6];
    o1.w = acc[r][7] + bias[n0 + col0 + 7];
    *(float4*)(Cout + (size_t)row * N + n0 + col0) = o0;
    *(float4*)(Cout + (size_t)row * N + n0 + col0 + 4) = o1;
  }
}

// K2: offsets GEMM; writes pixel-space x,y into smp[(row*8+h)*48 + lp*3 + {0,1}]
__global__ __launch_bounds__(256) void gemm_off_kernel(
    const float* __restrict__ Q, const float* __restrict__ Woff,
    const float* __restrict__ boff, const float* __restrict__ refp,
    float* __restrict__ smp) {
  __shared__ GemmSmem s;
  float acc[8][8];
  int row_base = blockIdx.x * TM;
  int n0 = blockIdx.y * TN;
  gemm_mainloop(Q, Woff, row_base, n0, 256, s, acc);
  const int t = threadIdx.x;
  const int tx = t & 15, ty = t >> 4;
  const int row0 = 8 * ty, col0 = 8 * tx;
#pragma unroll
  for (int r = 0; r < 8; ++r) {
    int row = row_base + row0 + r;
#pragma unroll
    for (int c2 = 0; c2 < 4; ++c2) {
      int gx = n0 + col0 + 2 * c2;          // even col: x; gx+1: y
      int pair = gx >> 1;                   // (h*4+l)*4+p
      int h = pair >> 4, lp = pair & 15, l = lp >> 2;
      float lw = (float)(64 >> l);          // square levels: W==H
      float ox = acc[r][2 * c2] + boff[gx];
      float oy = acc[r][2 * c2 + 1] + boff[gx + 1];
      float rx = refp[(size_t)row * 8 + l * 2];
      float ry = refp[(size_t)row * 8 + l * 2 + 1];
      size_t o = ((size_t)row * 8 + h) * 48 + lp * 3;
      smp[o]     = rx * lw + ox - 0.5f;     // == (rx + ox/W)*W - 0.5
      smp[o + 1] = ry * lw + oy - 0.5f;
    }
  }
}

// K3: attn GEMM (N=128) + pairwise-shuffle softmax (threads tx, tx^1 co-own one head)
__global__ __launch_bounds__(256) void gemm_attn_kernel(
    const float* __restrict__ Q, const float* __restrict__ Wattn,
    const float* __restrict__ battn, float* __restrict__ smp) {
  __shared__ GemmSmem s;
  float acc[8][8];
  int row_base = blockIdx.x * TM;
  gemm_mainloop(Q, Wattn, row_base, 0, 128, s, acc);
  const int t = threadIdx.x;
  const int tx = t & 15, ty = t >> 4;
  const int row0 = 8 * ty, col0 = 8 * tx;
  const int h = tx >> 1;        // head = col0/16
  const int sub = tx & 1;       // 0: cols 0-7 of head, 1: cols 8-15
#pragma unroll
  for (int r = 0; r < 8; ++r) {
    float x[8];
    float m = -1e30f;
#pragma unroll
    for (int c = 0; c < 8; ++c) {
      x[c] = acc[r][c] + battn[col0 + c];
      m = fmaxf(m, x[c]);
    }
    m = fmaxf(m, __shfl_xor(m, 1, 64));
    float ssum = 0.f;
#pragma unroll
    for (int c = 0; c < 8; ++c) { x[c] = __expf(x[c] - m); ssum += x[c]; }
    ssum += __shfl_xor(ssum, 1, 64);
    float inv = 1.f / ssum;
    size_t o = ((size_t)(row_base + row0 + r) * 8 + h) * 48 + sub * 24 + 2;
#pragma unroll
    for (int c = 0; c < 8; ++c) smp[o + 3 * c] = x[c] * inv;
  }
}

// K5: bilinear sampling core. One wave per (row, head); lanes 0-31: lp 0-7, lanes 32-63: lp 8-15.
__global__ __launch_bounds__(512) void core_kernel(
    const float* __restrict__ value, const float* __restrict__ smp,
    float* __restrict__ core) {
  const int brow = blockIdx.x;
  const int b = brow / LQ;
  const int t = threadIdx.x;
  const int h = t >> 6;
  const int lane = t & 63;
  const float* sp = smp + ((size_t)brow * 8 + h) * 48;
  float v = (lane < 48) ? sp[lane] : 0.f;
  const int d = lane & 31;
  const int half = lane >> 5;
  const float* vbase = value + (size_t)b * LIN * 256 + h * 32 + d;
  float acc = 0.f;
#pragma unroll
  for (int j = 0; j < 8; ++j) {
    int lp = j + (half << 3);
    float x  = __shfl(v, lp * 3 + 0, 64);
    float y  = __shfl(v, lp * 3 + 1, 64);
    float aw = __shfl(v, lp * 3 + 2, 64);
    int l = lp >> 2;
    int wdim = 64 >> l;
    int st = (l == 0) ? 0 : (l == 1) ? 4096 : (l == 2) ? 5120 : 5376;
    float fx0 = floorf(x), fy0 = floorf(y);
    float lx = x - fx0, ly = y - fy0;
    int x0 = (int)fx0, y0 = (int)fy0;
    int x1 = x0 + 1, y1 = y0 + 1;
    int cx0 = min(max(x0, 0), wdim - 1), cx1 = min(max(x1, 0), wdim - 1);
    int cy0 = min(max(y0, 0), wdim - 1), cy1 = min(max(y1, 0), wdim - 1);
    float vx0 = (x0 >= 0 && x0 < wdim) ? 1.f : 0.f;
    float vx1 = (x1 >= 0 && x1 < wdim) ? 1.f : 0.f;
    float vy0 = (y0 >= 0 && y0 < wdim) ? 1.f : 0.f;
    float vy1 = (y1 >= 0 && y1 < wdim) ? 1.f : 0.f;
    float w00 = (1.f - lx) * (1.f - ly) * vx0 * vy0;
    float w01 = lx * (1.f - ly) * vx1 * vy0;
    float w10 = (1.f - lx) * ly * vx0 * vy1;
    float w11 = lx * ly * vx1 * vy1;
    const float* vb = vbase + (size_t)st * 256;
    float s00 = vb[(size_t)(cy0 * wdim + cx0) * 256];
    float s01 = vb[(size_t)(cy0 * wdim + cx1) * 256];
    float s10 = vb[(size_t)(cy1 * wdim + cx0) * 256];
    float s11 = vb[(size_t)(cy1 * wdim + cx1) * 256];
    acc += aw * (w00 * s00 + w01 * s01 + w10 * s10 + w11 * s11);
  }
  acc += __shfl(acc, lane ^ 32, 64);
  if (lane < 32) core[(size_t)brow * 256 + h * 32 + d] = acc;
}

extern "C" void kernel_launch(void* const* d_in, const int* in_sizes, int n_in,
                              void* d_out, int out_size, void* d_ws, size_t ws_size,
                              hipStream_t stream) {
  const float* query  = (const float*)d_in[0];
  const float* refp   = (const float*)d_in[1];
  const float* inpf   = (const float*)d_in[2];
  const float* W_val  = (const float*)d_in[5];
  const float* b_val  = (const float*)d_in[6];
  const float* W_off  = (const float*)d_in[7];
  const float* b_off  = (const float*)d_in[8];
  const float* W_attn = (const float*)d_in[9];
  const float* b_attn = (const float*)d_in[10];
  const float* W_out  = (const float*)d_in[11];
  const float* b_out  = (const float*)d_in[12];

  char* ws = (char*)d_ws;
  float* value = (float*)ws;                                     // 43520*256 f32 = 44,564,480 B
  float* smp   = (float*)(ws + 44564480);                        // 43520*8*48 f32 = 66,846,720 B
  float* core  = (float*)(ws + 44564480 + 66846720);             // 44,564,480 B
  float* out   = (float*)d_out;

  dim3 blk(256);
  gemm_bias_kernel<<<dim3(ROWS / TM, 2), blk, 0, stream>>>(inpf, W_val, b_val, value, 256);
  gemm_off_kernel <<<dim3(ROWS / TM, 2), blk, 0, stream>>>(query, W_off, b_off, refp, smp);
  gemm_attn_kernel<<<dim3(ROWS / TM, 1), blk, 0, stream>>>(query, W_attn, b_attn, smp);
  core_kernel     <<<dim3(ROWS), dim3(512), 0, stream>>>(value, smp, core);
  gemm_bias_kernel<<<dim3(ROWS / TM, 2), blk, 0, stream>>>(core, W_out, b_out, out, 256);
}

// Round 3
// 387.766 us; speedup vs baseline: 3.3235x; 3.3235x over previous
//
#include <hip/hip_runtime.h>

typedef unsigned short ushort;
typedef unsigned int uint;
typedef __bf16 bf16x8 __attribute__((ext_vector_type(8)));
typedef float floatx4 __attribute__((ext_vector_type(4)));
typedef ushort ushort8 __attribute__((ext_vector_type(8)));

constexpr int LQ = 5440;
constexpr int ROWS = 43520;   // batch(8) * 5440

__device__ __forceinline__ ushort f2b(float f) {
  union { float f; uint i; } v; v.f = f;
  uint r = v.i + 0x7FFFu + ((v.i >> 16) & 1u);
  return (ushort)(r >> 16);
}
__device__ __forceinline__ float blo(uint u) {
  union { uint i; float f; } v; v.i = u << 16; return v.f;
}
__device__ __forceinline__ float bhi(uint u) {
  union { uint i; float f; } v; v.i = u & 0xFFFF0000u; return v.f;
}

// ---------------- weight transpose + cast: Wt[n][k] bf16 ----------------
__global__ __launch_bounds__(256) void wcast_kernel(
    const float* __restrict__ Wv, const float* __restrict__ Wo,
    const float* __restrict__ Wa, const float* __restrict__ Wu,
    ushort* __restrict__ Wt) {
  int k = threadIdx.x;    // 0..255
  int n = blockIdx.x;     // 0..255
  int m = blockIdx.y;     // 0..3
  const float* src = (m == 0) ? Wv : (m == 1) ? Wo : (m == 2) ? Wa : Wu;
  int N = (m == 2) ? 128 : 256;
  if (n >= N) return;
  size_t off = (size_t)m * 65536 - ((m == 3) ? 32768 : 0);  // 0,65536,131072,163840
  Wt[off + (size_t)n * 256 + k] = f2b(src[(size_t)k * N + n]);
}

// ---------------- MFMA 128x128 tile mainloop (K=256, BK=32) ----------------
// A: [M][256] fp32 (or bf16 if ABF16), Bt: [N][256] bf16 (pre-transposed weights)
// A-frag: A[m=lane&15][k=quad*8+j]; B-frag: B[k=quad*8+j][n=lane&15]
// C/D:    col=lane&15, row=quad*4+reg
template<bool ABF16>
__device__ __forceinline__ void mfma_128x128(
    const void* __restrict__ Av, const ushort* __restrict__ Bt,
    int row_base, int n0, ushort* At, ushort* Bs, floatx4 (&acc)[4][4]) {
  const int t = threadIdx.x;
  const int r = t >> 1, half = t & 1;
  const int lane = t & 63, wv = t >> 6;
  const int quad = lane >> 4, l15 = lane & 15;
  const int m0w = (wv >> 1) * 64, n0w = (wv & 1) * 64;
#pragma unroll
  for (int i = 0; i < 4; ++i)
#pragma unroll
    for (int j = 0; j < 4; ++j) acc[i][j] = floatx4{0.f, 0.f, 0.f, 0.f};

  for (int k0 = 0; k0 < 256; k0 += 32) {
    if (ABF16) {
      const ushort* ap = (const ushort*)Av + (size_t)(row_base + r) * 256 + k0 + half * 16;
      *(ushort8*)&At[r * 32 + half * 16]     = *(const ushort8*)ap;
      *(ushort8*)&At[r * 32 + half * 16 + 8] = *(const ushort8*)(ap + 8);
    } else {
      const float* ap = (const float*)Av + (size_t)(row_base + r) * 256 + k0 + half * 16;
      float4 a0 = *(const float4*)ap,       a1 = *(const float4*)(ap + 4);
      float4 a2 = *(const float4*)(ap + 8), a3 = *(const float4*)(ap + 12);
      ushort8 u0, u1;
      u0[0] = f2b(a0.x); u0[1] = f2b(a0.y); u0[2] = f2b(a0.z); u0[3] = f2b(a0.w);
      u0[4] = f2b(a1.x); u0[5] = f2b(a1.y); u0[6] = f2b(a1.z); u0[7] = f2b(a1.w);
      u1[0] = f2b(a2.x); u1[1] = f2b(a2.y); u1[2] = f2b(a2.z); u1[3] = f2b(a2.w);
      u1[4] = f2b(a3.x); u1[5] = f2b(a3.y); u1[6] = f2b(a3.z); u1[7] = f2b(a3.w);
      *(ushort8*)&At[r * 32 + half * 16]     = u0;
      *(ushort8*)&At[r * 32 + half * 16 + 8] = u1;
    }
    {
      const ushort* bp = Bt + (size_t)(n0 + r) * 256 + k0 + half * 16;
      *(ushort8*)&Bs[r * 32 + half * 16]     = *(const ushort8*)bp;
      *(ushort8*)&Bs[r * 32 + half * 16 + 8] = *(const ushort8*)(bp + 8);
    }
    __syncthreads();
    bf16x8 af[4], bfv[4];
#pragma unroll
    for (int ti = 0; ti < 4; ++ti)
      af[ti] = *(const bf16x8*)&At[(m0w + ti * 16 + l15) * 32 + quad * 8];
#pragma unroll
    for (int tj = 0; tj < 4; ++tj)
      bfv[tj] = *(const bf16x8*)&Bs[(n0w + tj * 16 + l15) * 32 + quad * 8];
#pragma unroll
    for (int ti = 0; ti < 4; ++ti)
#pragma unroll
      for (int tj = 0; tj < 4; ++tj)
        acc[ti][tj] = __builtin_amdgcn_mfma_f32_16x16x32_bf16(af[ti], bfv[tj], acc[ti][tj], 0, 0, 0);
    __syncthreads();
  }
}

// ---------------- K1: value GEMM -> bf16 value[row][256] ----------------
__global__ __launch_bounds__(256) void gemm_val_kernel(
    const float* __restrict__ X, const ushort* __restrict__ WtV,
    const float* __restrict__ bval, ushort* __restrict__ value) {
  __shared__ ushort At[4096];
  __shared__ ushort Bs[4096];
  floatx4 acc[4][4];
  int row_base = blockIdx.x * 128, n0 = blockIdx.y * 128;
  mfma_128x128<false>(X, WtV, row_base, n0, At, Bs, acc);
  const int t = threadIdx.x, lane = t & 63, wv = t >> 6;
  const int quad = lane >> 4, l15 = lane & 15;
  const int m0w = (wv >> 1) * 64, n0w = (wv & 1) * 64;
#pragma unroll
  for (int tj = 0; tj < 4; ++tj) {
    int gcol = n0 + n0w + tj * 16 + l15;
    float b = bval[gcol];
#pragma unroll
    for (int ti = 0; ti < 4; ++ti)
#pragma unroll
      for (int reg = 0; reg < 4; ++reg) {
        int grow = row_base + m0w + ti * 16 + quad * 4 + reg;
        value[(size_t)grow * 256 + gcol] = f2b(acc[ti][tj][reg] + b);
      }
  }
}

// ---------------- K2: offset GEMM -> park pixel x,y in table slots ----------------
__global__ __launch_bounds__(256) void gemm_off_kernel(
    const float* __restrict__ Q, const ushort* __restrict__ WtO,
    const float* __restrict__ boff, const float* __restrict__ refp,
    float* __restrict__ tblf) {
  __shared__ ushort At[4096];
  __shared__ ushort Bs[4096];
  floatx4 acc[4][4];
  int row_base = blockIdx.x * 128, n0 = blockIdx.y * 128;
  mfma_128x128<false>(Q, WtO, row_base, n0, At, Bs, acc);
  const int t = threadIdx.x, lane = t & 63, wv = t >> 6;
  const int quad = lane >> 4, l15 = lane & 15;
  const int m0w = (wv >> 1) * 64, n0w = (wv & 1) * 64;
#pragma unroll
  for (int tj = 0; tj < 4; ++tj) {
    int gcol = n0 + n0w + tj * 16 + l15;
    float b = boff[gcol];
    int pair = gcol >> 1, xy = gcol & 1;
    int hh = pair >> 4, lp = pair & 15, l = lp >> 2;
    float lw = (float)(64 >> l);
#pragma unroll
    for (int ti = 0; ti < 4; ++ti)
#pragma unroll
      for (int reg = 0; reg < 4; ++reg) {
        int grow = row_base + m0w + ti * 16 + quad * 4 + reg;
        float ref = refp[(size_t)grow * 8 + l * 2 + xy];
        float o = acc[ti][tj][reg] + b;
        tblf[(((size_t)grow * 8 + hh) * 16 + lp) * 4 + xy] = ref * lw + o - 0.5f;
      }
  }
}

// ---------------- K3: attn GEMM + softmax + finalize sampling table ----------------
// slot = {idx00|idx01<<16, idx10|idx11<<16, bf16(w00*aw)|bf16(w01*aw)<<16, bf16(w10*aw)|bf16(w11*aw)<<16}
__global__ __launch_bounds__(256) void gemm_attn_kernel(
    const float* __restrict__ Q, const ushort* __restrict__ WtA,
    const float* __restrict__ battn, uint4* __restrict__ tbl) {
  __shared__ ushort At[4096];
  __shared__ ushort Bs[4096];
  floatx4 acc[4][4];
  int row_base = blockIdx.x * 128;
  mfma_128x128<false>(Q, WtA, row_base, 0, At, Bs, acc);
  const int t = threadIdx.x, lane = t & 63, wv = t >> 6;
  const int quad = lane >> 4, l15 = lane & 15;
  const int m0w = (wv >> 1) * 64;
  const int headbase = (wv & 1) * 4;
  const int lp = l15, l = lp >> 2;
  const int wd = 64 >> l;
  const int st = (l >= 1 ? 4096 : 0) + (l >= 2 ? 1024 : 0) + (l >= 3 ? 256 : 0);
#pragma unroll
  for (int tj = 0; tj < 4; ++tj) {
    int h = headbase + tj;
    float bia = battn[h * 16 + lp];
#pragma unroll
    for (int ti = 0; ti < 4; ++ti)
#pragma unroll
      for (int reg = 0; reg < 4; ++reg) {
        int grow = row_base + m0w + ti * 16 + quad * 4 + reg;
        float x = acc[ti][tj][reg] + bia;
        float m = x;
        m = fmaxf(m, __shfl_xor(m, 1, 64));
        m = fmaxf(m, __shfl_xor(m, 2, 64));
        m = fmaxf(m, __shfl_xor(m, 4, 64));
        m = fmaxf(m, __shfl_xor(m, 8, 64));
        float e = __expf(x - m);
        float s = e;
        s += __shfl_xor(s, 1, 64);
        s += __shfl_xor(s, 2, 64);
        s += __shfl_xor(s, 4, 64);
        s += __shfl_xor(s, 8, 64);
        float aw = e / s;
        uint4* slot = &tbl[((size_t)grow * 8 + h) * 16 + lp];
        uint4 sv = *slot;
        float xx = __uint_as_float(sv.x), yy = __uint_as_float(sv.y);
        float fx = floorf(xx), fy = floorf(yy);
        float lx = xx - fx, ly = yy - fy;
        int x0 = (int)fx, y0 = (int)fy, x1 = x0 + 1, y1 = y0 + 1;
        int cx0 = min(max(x0, 0), wd - 1), cx1 = min(max(x1, 0), wd - 1);
        int cy0 = min(max(y0, 0), wd - 1), cy1 = min(max(y1, 0), wd - 1);
        float vx0 = (x0 >= 0 && x0 < wd) ? 1.f : 0.f;
        float vx1 = (x1 >= 0 && x1 < wd) ? 1.f : 0.f;
        float vy0 = (y0 >= 0 && y0 < wd) ? 1.f : 0.f;
        float vy1 = (y1 >= 0 && y1 < wd) ? 1.f : 0.f;
        float g00 = (1.f - lx) * (1.f - ly) * vx0 * vy0 * aw;
        float g01 = lx * (1.f - ly) * vx1 * vy0 * aw;
        float g10 = (1.f - lx) * ly * vx0 * vy1 * aw;
        float g11 = lx * ly * vx1 * vy1 * aw;
        uint i00 = st + cy0 * wd + cx0, i01 = st + cy0 * wd + cx1;
        uint i10 = st + cy1 * wd + cx0, i11 = st + cy1 * wd + cx1;
        uint4 ov;
        ov.x = i00 | (i01 << 16);
        ov.y = i10 | (i11 << 16);
        ov.z = (uint)f2b(g00) | ((uint)f2b(g01) << 16);
        ov.w = (uint)f2b(g10) | ((uint)f2b(g11) << 16);
        *slot = ov;
      }
  }
}

// ---------------- K5: bilinear core. wave=(row,h); lane = quad(lp-group)*16 + d2 ----------------
__global__ __launch_bounds__(512) void core_kernel(
    const ushort* __restrict__ value, const uint* __restrict__ tbl,
    uint* __restrict__ coreo) {
  const int brow = blockIdx.x;
  const int b = brow / LQ;
  const int t = threadIdx.x;
  const int h = t >> 6, lane = t & 63;
  const int d2 = lane & 15;
  const uint v = tbl[((size_t)brow * 8 + h) * 64 + lane];
  const uint* vb = (const uint*)(value + (size_t)b * (LQ * 256)) + h * 16 + d2;
  float acc0 = 0.f, acc1 = 0.f;
#pragma unroll
  for (int j = 0; j < 4; ++j) {
    uint i01 = (uint)__shfl((int)v, (lane & 48) | (4 * j + 0), 64);
    uint i23 = (uint)__shfl((int)v, (lane & 48) | (4 * j + 1), 64);
    uint wab = (uint)__shfl((int)v, (lane & 48) | (4 * j + 2), 64);
    uint wcd = (uint)__shfl((int)v, (lane & 48) | (4 * j + 3), 64);
    uint s00 = vb[(i01 & 0xFFFFu) * 128];
    uint s01 = vb[(i01 >> 16) * 128];
    uint s10 = vb[(i23 & 0xFFFFu) * 128];
    uint s11 = vb[(i23 >> 16) * 128];
    float f00 = blo(wab), f01 = bhi(wab), f10 = blo(wcd), f11 = bhi(wcd);
    acc0 = fmaf(f00, blo(s00), acc0); acc1 = fmaf(f00, bhi(s00), acc1);
    acc0 = fmaf(f01, blo(s01), acc0); acc1 = fmaf(f01, bhi(s01), acc1);
    acc0 = fmaf(f10, blo(s10), acc0); acc1 = fmaf(f10, bhi(s10), acc1);
    acc0 = fmaf(f11, blo(s11), acc0); acc1 = fmaf(f11, bhi(s11), acc1);
  }
  acc0 += __shfl_xor(acc0, 16, 64); acc0 += __shfl_xor(acc0, 32, 64);
  acc1 += __shfl_xor(acc1, 16, 64); acc1 += __shfl_xor(acc1, 32, 64);
  if (lane < 16) {
    uint p = (uint)f2b(acc0) | ((uint)f2b(acc1) << 16);
    coreo[((size_t)brow * 8 + h) * 16 + d2] = p;
  }
}

// ---------------- K4: out GEMM (A = core bf16) -> fp32 d_out ----------------
__global__ __launch_bounds__(256) void gemm_out_kernel(
    const ushort* __restrict__ C, const ushort* __restrict__ WtU,
    const float* __restrict__ bout, float* __restrict__ out) {
  __shared__ ushort At[4096];
  __shared__ ushort Bs[4096];
  floatx4 acc[4][4];
  int row_base = blockIdx.x * 128, n0 = blockIdx.y * 128;
  mfma_128x128<true>(C, WtU, row_base, n0, At, Bs, acc);
  const int t = threadIdx.x, lane = t & 63, wv = t >> 6;
  const int quad = lane >> 4, l15 = lane & 15;
  const int m0w = (wv >> 1) * 64, n0w = (wv & 1) * 64;
#pragma unroll
  for (int tj = 0; tj < 4; ++tj) {
    int gcol = n0 + n0w + tj * 16 + l15;
    float b = bout[gcol];
#pragma unroll
    for (int ti = 0; ti < 4; ++ti)
#pragma unroll
      for (int reg = 0; reg < 4; ++reg) {
        int grow = row_base + m0w + ti * 16 + quad * 4 + reg;
        out[(size_t)grow * 256 + gcol] = acc[ti][tj][reg] + b;
      }
  }
}

extern "C" void kernel_launch(void* const* d_in, const int* in_sizes, int n_in,
                              void* d_out, int out_size, void* d_ws, size_t ws_size,
                              hipStream_t stream) {
  const float* query  = (const float*)d_in[0];
  const float* refp   = (const float*)d_in[1];
  const float* inpf   = (const float*)d_in[2];
  const float* W_val  = (const float*)d_in[5];
  const float* b_val  = (const float*)d_in[6];
  const float* W_off  = (const float*)d_in[7];
  const float* b_off  = (const float*)d_in[8];
  const float* W_attn = (const float*)d_in[9];
  const float* b_attn = (const float*)d_in[10];
  const float* W_out  = (const float*)d_in[11];
  const float* b_out  = (const float*)d_in[12];

  char* ws = (char*)d_ws;
  ushort* Wt    = (ushort*)ws;                                    // 458,752 B used
  ushort* value = (ushort*)(ws + 1048576);                        // 22,282,240 B
  uint*   tbl   = (uint*)(ws + 1048576 + 22282240);               // 89,128,960 B
  uint*   coreo = (uint*)(ws + 1048576 + 22282240 + 89128960);    // 22,282,240 B
  // total 134,742,016 B

  dim3 blk(256);
  wcast_kernel    <<<dim3(256, 4), blk, 0, stream>>>(W_val, W_off, W_attn, W_out, Wt);
  gemm_val_kernel <<<dim3(ROWS / 128, 2), blk, 0, stream>>>(inpf, Wt, b_val, value);
  gemm_off_kernel <<<dim3(ROWS / 128, 2), blk, 0, stream>>>(query, Wt + 65536, b_off, refp, (float*)tbl);
  gemm_attn_kernel<<<dim3(ROWS / 128, 1), blk, 0, stream>>>(query, Wt + 131072, b_attn, (uint4*)tbl);
  core_kernel     <<<dim3(ROWS), dim3(512), 0, stream>>>(value, tbl, coreo);
  gemm_out_kernel <<<dim3(ROWS / 128, 2), blk, 0, stream>>>((const ushort*)coreo, Wt + 163840, b_out, (float*)d_out);
}